// Round 8
// baseline (732.414 us; speedup 1.0000x reference)
//
#include <hip/hip_runtime.h>
#include <hip/hip_bf16.h>

// ---------------------------------------------------------------------------
// EnhancedTernaryLinear: out = (x @ W^T) * scale + bias
// M=8192, N=4096, K=4096. x->bf16, W(ternary)->bf16, then 256x256 MFMA GEMM.
// R8: R5 pipeline + 32x32x16 MFMA, with CORRECT k-step addressing: the four
// k-chunk addresses are base ^ {0,32,64,96} (XOR-stepped registers), since
// additive immediates collide with the (row&7)<<4 swizzle bits. bF0n dropped
// (read into bF0 post-MFMA in q3) to stay under the 256-reg / 2-wave budget.
// ---------------------------------------------------------------------------

#define M_DIM 8192
#define N_DIM 4096
#define K_DIM 4096
#define BK 64
#define NT (K_DIM / BK)   // 64 K-tiles

typedef __attribute__((ext_vector_type(8))) short bf16x8;
typedef __attribute__((ext_vector_type(16))) float f32x16;

__device__ __forceinline__ unsigned short f2bf(float f) {
  unsigned int u = __float_as_uint(f);
  unsigned int r = (u + 0x7FFFu + ((u >> 16) & 1u)) >> 16;
  return (unsigned short)r;
}

__device__ __forceinline__ void async16(const void* g, void* l) {
  __builtin_amdgcn_global_load_lds(
      (const __attribute__((address_space(1))) void*)g,
      (__attribute__((address_space(3))) void*)l, 16, 0, 0);
}

// ---------------- conversion kernels ----------------

__global__ void cvt_x_kernel(const float* __restrict__ x,
                             unsigned short* __restrict__ xb, long n) {
  long i0 = ((long)blockIdx.x * blockDim.x + threadIdx.x) * 8;
  long stride = (long)gridDim.x * blockDim.x * 8;
  for (long i = i0; i < n; i += stride) {
    float4 v0 = *(const float4*)(x + i);
    float4 v1 = *(const float4*)(x + i + 4);
    bf16x8 o;
    o[0] = (short)f2bf(v0.x); o[1] = (short)f2bf(v0.y);
    o[2] = (short)f2bf(v0.z); o[3] = (short)f2bf(v0.w);
    o[4] = (short)f2bf(v1.x); o[5] = (short)f2bf(v1.y);
    o[6] = (short)f2bf(v1.z); o[7] = (short)f2bf(v1.w);
    *(bf16x8*)(xb + i) = o;
  }
}

__device__ __forceinline__ unsigned short i2bf(int v) {
  return v == 0 ? (unsigned short)0
                : (v > 0 ? (unsigned short)0x3F80 : (unsigned short)0xBF80);
}

__global__ void cvt_w_kernel(const int* __restrict__ w,
                             unsigned short* __restrict__ wb, long n) {
  long i0 = ((long)blockIdx.x * blockDim.x + threadIdx.x) * 8;
  long stride = (long)gridDim.x * blockDim.x * 8;
  for (long i = i0; i < n; i += stride) {
    int4 a = *(const int4*)(w + i);
    int4 b = *(const int4*)(w + i + 4);
    bf16x8 o;
    o[0] = (short)i2bf(a.x); o[1] = (short)i2bf(a.y);
    o[2] = (short)i2bf(a.z); o[3] = (short)i2bf(a.w);
    o[4] = (short)i2bf(b.x); o[5] = (short)i2bf(b.y);
    o[6] = (short)i2bf(b.z); o[7] = (short)i2bf(b.w);
    *(bf16x8*)(wb + i) = o;
  }
}

// ---------------- 256x256 GEMM, 32x32x16 frags ----------------
// 512 threads = 8 waves (2 wr x 4 wc). Wave tile 128x64: 4 m-frags x 2 n-frags
// of 32x32 (acc = 8 x f32x16 = 128 AGPR).
// LDS (bytes), 128 KiB: A(b,mh) = b*65536 + mh*16384  (128 rows x 128 B)
//               B(b,nh) = b*65536 + 32768 + nh*16384. Row = 64 bf16 = 128 B.
// Swizzle: stored_byte = logical_byte ^ ((row&7)<<4). Stage: inverse-swizzled
// GLOBAL source + linear LDS dest. Read: per-lane col = (kf<<5)^(l5*16)^(l7<<4)
// -> 4 XOR-stepped base regs (base ^ {0,32,64,96}); mh/mi/nh steps additive
// (bits >=12, no collision).
// Frag layout 32x32x16: A/B lane l: row/col = l&31, k = (l>>5)*8 + i (8 contig).
// C/D: col = lane&31, row = (reg&3) + 8*(reg>>2) + 4*(lane>>5).
// Phases per tile T (buf b) — R5's schedule:
//   q0: MFMA(aFx,bF0); issue bF1 [4];       stage B-nh0(T+1); LGKM(4)
//   q1: MFMA(aFx,bF1); issue aFy [8];       stage A-mh0(T+2); LGKM(8)
//   q2: MFMA(aFy,bF1); no reads;            stage B-nh1(T+2); LGKM(0); VMW(4)
//   q3: MFMA(aFy,bF0); issue aFx'(T+1) [8] pre-MFMA, bF0(T+1) [4] post-MFMA;
//       stage A-mh1(T+2); LGKM(8)

#define AOFFs(b, mh) ((b)*32768 + (mh)*8192)            // shorts
#define BOFFs(b, nh) ((b)*32768 + 16384 + (nh)*8192)    // shorts

__device__ __forceinline__ void stage_A_half(const unsigned short* __restrict__ A,
                                             int grow0, int ktE, int mh,
                                             unsigned short* lds_region, int t) {
  const int colb = (t & 7) * 16;
  const int swz = ((t >> 3) & 7) << 4;
  const int scol = (colb ^ swz) >> 1;
#pragma unroll
  for (int rr = 0; rr < 2; ++rr) {
    int rho = rr * 64 + (t >> 3);
    int r = ((rho >> 6) << 7) + mh * 64 + (rho & 63);
    async16(A + (size_t)(grow0 + r) * K_DIM + ktE + scol,
            lds_region + rr * 4096 + t * 8);
  }
}

__device__ __forceinline__ void stage_B_half(const unsigned short* __restrict__ B,
                                             int gcol0, int ktE, int nh,
                                             unsigned short* lds_region, int t) {
  const int colb = (t & 7) * 16;
  const int swz = ((t >> 3) & 7) << 4;
  const int scol = (colb ^ swz) >> 1;
#pragma unroll
  for (int rr = 0; rr < 2; ++rr) {
    int rho = rr * 64 + (t >> 3);
    int c = ((rho >> 5) << 6) + nh * 32 + (rho & 31);
    async16(B + (size_t)(gcol0 + c) * K_DIM + ktE + scol,
            lds_region + rr * 4096 + t * 8);
  }
}

#define DSR(dst, base, OFF)                                     \
  asm volatile("ds_read_b128 %0, %1 offset:" OFF                \
               : "=v"(dst) : "v"(base))

// A half: 2 m-frags (imm OM0/OM1 = region + mi*4096) x 4 kf (XOR bases)
#define RD_A2(k0, k1, k2, k3, AF, OM0, OM1)                      \
  do {                                                           \
    DSR(AF[0][0], (k0), OM0); DSR(AF[0][1], (k1), OM0);          \
    DSR(AF[0][2], (k2), OM0); DSR(AF[0][3], (k3), OM0);          \
    DSR(AF[1][0], (k0), OM1); DSR(AF[1][1], (k1), OM1);          \
    DSR(AF[1][2], (k2), OM1); DSR(AF[1][3], (k3), OM1);          \
  } while (0)
// B: 1 n-frag x 4 kf
#define RD_B1(k0, k1, k2, k3, BF, ON)                            \
  do {                                                           \
    DSR(BF[0], (k0), ON); DSR(BF[1], (k1), ON);                  \
    DSR(BF[2], (k2), ON); DSR(BF[3], (k3), ON);                  \
  } while (0)

#define LGKM(N)                                                  \
  asm volatile("s_waitcnt lgkmcnt(" #N ")" ::: "memory");        \
  __builtin_amdgcn_sched_barrier(0)
#define VMW(N) asm volatile("s_waitcnt vmcnt(" #N ")" ::: "memory")

#define MFMA8(AF, BF, MH, NH)                                                  \
  do {                                                                         \
    __builtin_amdgcn_s_setprio(1);                                             \
    _Pragma("unroll") for (int kf = 0; kf < 4; ++kf)                           \
    _Pragma("unroll") for (int mi = 0; mi < 2; ++mi)                           \
      acc[(MH)*2 + mi][NH] = __builtin_amdgcn_mfma_f32_32x32x16_bf16(          \
          AF[mi][kf], BF[kf], acc[(MH)*2 + mi][NH], 0, 0, 0);                  \
    __builtin_amdgcn_s_setprio(0);                                             \
    __builtin_amdgcn_sched_barrier(0);                                         \
  } while (0)

// One K-tile, buf BI (compile-time 0/1). CB/NB = current/next buf byte bases.
#define TILE(TT, BI)                                                           \
  do {                                                                         \
    const int T_ = (TT);                                                       \
    const unsigned CB = (BI) * 65536u, NB = ((BI) ^ 1) * 65536u;               \
    /* q0 */                                                                   \
    RD_B1(bK0 + CB, bK1 + CB, bK2 + CB, bK3 + CB, bF1, "16384");               \
    if (T_ + 1 < NT)                                                           \
      stage_B_half(B, bcol, (T_ + 1) * BK, 0, lds + BOFFs((BI) ^ 1, 0), t);    \
    LGKM(4);                                                                   \
    MFMA8(aFx, bF0, 0, 0);                                                     \
    __builtin_amdgcn_s_barrier();                                              \
    /* q1 */                                                                   \
    RD_A2(aK0 + CB, aK1 + CB, aK2 + CB, aK3 + CB, aFy, "16384", "20480");      \
    if (T_ + 2 < NT)                                                           \
      stage_A_half(A, brow, (T_ + 2) * BK, 0, lds + AOFFs(BI, 0), t);          \
    LGKM(8);                                                                   \
    MFMA8(aFx, bF1, 0, 1);                                                     \
    __builtin_amdgcn_s_barrier();                                              \
    /* q2 */                                                                   \
    if (T_ + 2 < NT)                                                           \
      stage_B_half(B, bcol, (T_ + 2) * BK, 1, lds + BOFFs(BI, 1), t);          \
    LGKM(0);                                                                   \
    MFMA8(aFy, bF1, 1, 1);                                                     \
    if (T_ < NT - 2) { VMW(4); }                                               \
    else if (T_ == NT - 2) { VMW(0); }                                         \
    __builtin_amdgcn_s_barrier();                                              \
    /* q3 */                                                                   \
    if (T_ + 1 < NT) {                                                         \
      RD_A2(aK0 + NB, aK1 + NB, aK2 + NB, aK3 + NB, aFx, "0", "4096");         \
      if (T_ + 2 < NT)                                                         \
        stage_A_half(A, brow, (T_ + 2) * BK, 1, lds + AOFFs(BI, 1), t);        \
      LGKM(8);                                                                 \
      MFMA8(aFy, bF0, 1, 0);                                                   \
      RD_B1(bK0 + NB, bK1 + NB, bK2 + NB, bK3 + NB, bF0, "0");                 \
    } else {                                                                   \
      LGKM(0);                                                                 \
      MFMA8(aFy, bF0, 1, 0);                                                   \
    }                                                                          \
    __builtin_amdgcn_s_barrier();                                              \
  } while (0)

__global__ void __launch_bounds__(512, 2)
gemm_bt_kernel(const unsigned short* __restrict__ A,  // bf16 [M][K]
               const unsigned short* __restrict__ B,  // bf16 [N][K]
               const float* __restrict__ scale, const float* __restrict__ bias,
               float* __restrict__ C) {
  __shared__ unsigned short lds[65536];  // 128 KiB

  const int t = threadIdx.x;
  const int bid = blockIdx.x;
  const int swz = (bid & 7) * 64 + (bid >> 3);  // 512 wgs, 64/XCD (bijective)
  const int bm = swz >> 4;  // 32 M-tiles
  const int bn = swz & 15;  // 16 N-tiles
  const int brow = bm * 256, bcol = bn * 256;

  const int wid = t >> 6, lane = t & 63;
  const int wr = wid >> 2, wc = wid & 3;
  const int l31 = lane & 31, l5 = lane >> 5, l7 = lane & 7;

  // XOR-stepped k-chunk read bases (buf0); buf1 = +65536 (folded by TILE)
  const unsigned ldsb = (unsigned)(unsigned long long)&lds[0];
  const unsigned colb = ((unsigned)(l5 * 16)) ^ ((unsigned)(l7 << 4));
  const unsigned aK0 = ldsb + (unsigned)((wr * 64 + l31) * 128) + colb;
  const unsigned aK1 = aK0 ^ 32u, aK2 = aK0 ^ 64u, aK3 = aK0 ^ 96u;
  const unsigned bK0 = ldsb + 32768u + (unsigned)((wc * 32 + l31) * 128) + colb;
  const unsigned bK1 = bK0 ^ 32u, bK2 = bK0 ^ 64u, bK3 = bK0 ^ 96u;

  f32x16 acc[4][2] = {};
  bf16x8 aFx[2][4], aFy[2][4], bF0[4], bF1[4];

  // ---- prologue: tile0 (4 halves) + tile1 {A-mh0, B-nh1, A-mh1} ----
  stage_A_half(A, brow, 0, 0, lds + AOFFs(0, 0), t);
  stage_B_half(B, bcol, 0, 1, lds + BOFFs(0, 1), t);
  stage_A_half(A, brow, 0, 1, lds + AOFFs(0, 1), t);
  stage_B_half(B, bcol, 0, 0, lds + BOFFs(0, 0), t);
  stage_A_half(A, brow, BK, 0, lds + AOFFs(1, 0), t);
  stage_B_half(B, bcol, BK, 1, lds + BOFFs(1, 1), t);
  stage_A_half(A, brow, BK, 1, lds + AOFFs(1, 1), t);
  VMW(6);  // tile0's 8 stage-loads landed
  __builtin_amdgcn_s_barrier();
  RD_A2(aK0, aK1, aK2, aK3, aFx, "0", "4096");  // tile0 mh0
  RD_B1(bK0, bK1, bK2, bK3, bF0, "0");          // tile0 nh0 (12 outstanding)

  for (int T = 0; T < NT; T += 2) {
    TILE(T, 0);
    TILE(T + 1, 1);
  }

  // ---- epilogue: scale/bias; 32x32 C/D layout ----
#pragma unroll
  for (int ni = 0; ni < 2; ++ni) {
    const int gc = bcol + wc * 64 + ni * 32 + l31;
    const float s = scale[gc];
    const float bo = bias[gc];
#pragma unroll
    for (int mi = 0; mi < 4; ++mi) {
      const int gr = brow + wr * 128 + mi * 32 + 4 * l5;
#pragma unroll
      for (int r = 0; r < 16; ++r) {
        const int row = (r & 3) + 8 * (r >> 2);
        C[(size_t)(gr + row) * N_DIM + gc] = acc[mi][ni][r] * s + bo;
      }
    }
  }
}

// ---------------- naive fallback (only if ws too small) ----------------

__global__ void naive_kernel(const float* __restrict__ x, const int* __restrict__ w,
                             const float* __restrict__ sc, const float* __restrict__ bi,
                             float* __restrict__ out) {
  size_t idx = (size_t)blockIdx.x * blockDim.x + threadIdx.x;
  int m = (int)(idx >> 12);
  int n = (int)(idx & 4095);
  const float* xr = x + (size_t)m * K_DIM;
  const int* wr = w + (size_t)n * K_DIM;
  float acc = 0.f;
  for (int k = 0; k < K_DIM; ++k) acc = fmaf(xr[k], (float)wr[k], acc);
  out[idx] = acc * sc[n] + bi[n];
}

extern "C" void kernel_launch(void* const* d_in, const int* in_sizes, int n_in,
                              void* d_out, int out_size, void* d_ws, size_t ws_size,
                              hipStream_t stream) {
  const float* x = (const float*)d_in[0];
  const int* w = (const int*)d_in[1];
  const float* scale = (const float*)d_in[2];
  const float* bias = (const float*)d_in[3];
  float* out = (float*)d_out;

  const long nx = (long)M_DIM * K_DIM;
  const long nw = (long)N_DIM * K_DIM;
  const size_t need = (size_t)nx * 2 + (size_t)nw * 2;  // 96 MiB

  if (ws_size >= need) {
    unsigned short* xb = (unsigned short*)d_ws;
    unsigned short* wb = xb + nx;
    cvt_x_kernel<<<2048, 256, 0, stream>>>(x, xb, nx);
    cvt_w_kernel<<<2048, 256, 0, stream>>>(w, wb, nw);
    gemm_bt_kernel<<<512, 512, 0, stream>>>(xb, wb, scale, bias, out);
  } else {
    naive_kernel<<<((long)M_DIM * N_DIM) / 256, 256, 0, stream>>>(x, w, scale, bias, out);
  }
}

// Round 9
// 422.428 us; speedup vs baseline: 1.7338x; 1.7338x over previous
//
#include <hip/hip_runtime.h>
#include <hip/hip_bf16.h>

// ---------------------------------------------------------------------------
// EnhancedTernaryLinear: out = (x @ W^T) * scale + bias
// M=8192, N=4096, K=4096. x->bf16, W(ternary)->bf16, then 256x256 MFMA GEMM.
// R9: R5's proven 4-phase read-ahead pipeline (16x16x32 frags), but B
// fragments load DIRECT from global/L2 (global_load_dwordx4 per lane),
// eliminating B's LDS round-trip (LDS read traffic 196->128 KB/tile at the
// measured 85 B/cyc b128 rate). A stays LDS-staged + XOR-swizzled.
// ---------------------------------------------------------------------------

#define M_DIM 8192
#define N_DIM 4096
#define K_DIM 4096
#define BK 64
#define NT (K_DIM / BK)   // 64 K-tiles

typedef __attribute__((ext_vector_type(8))) short bf16x8;
typedef __attribute__((ext_vector_type(4))) float f32x4;

__device__ __forceinline__ unsigned short f2bf(float f) {
  unsigned int u = __float_as_uint(f);
  unsigned int r = (u + 0x7FFFu + ((u >> 16) & 1u)) >> 16;
  return (unsigned short)r;
}

__device__ __forceinline__ void async16(const void* g, void* l) {
  __builtin_amdgcn_global_load_lds(
      (const __attribute__((address_space(1))) void*)g,
      (__attribute__((address_space(3))) void*)l, 16, 0, 0);
}

// ---------------- conversion kernels ----------------

__global__ void cvt_x_kernel(const float* __restrict__ x,
                             unsigned short* __restrict__ xb, long n) {
  long i0 = ((long)blockIdx.x * blockDim.x + threadIdx.x) * 8;
  long stride = (long)gridDim.x * blockDim.x * 8;
  for (long i = i0; i < n; i += stride) {
    float4 v0 = *(const float4*)(x + i);
    float4 v1 = *(const float4*)(x + i + 4);
    bf16x8 o;
    o[0] = (short)f2bf(v0.x); o[1] = (short)f2bf(v0.y);
    o[2] = (short)f2bf(v0.z); o[3] = (short)f2bf(v0.w);
    o[4] = (short)f2bf(v1.x); o[5] = (short)f2bf(v1.y);
    o[6] = (short)f2bf(v1.z); o[7] = (short)f2bf(v1.w);
    *(bf16x8*)(xb + i) = o;
  }
}

__device__ __forceinline__ unsigned short i2bf(int v) {
  return v == 0 ? (unsigned short)0
                : (v > 0 ? (unsigned short)0x3F80 : (unsigned short)0xBF80);
}

__global__ void cvt_w_kernel(const int* __restrict__ w,
                             unsigned short* __restrict__ wb, long n) {
  long i0 = ((long)blockIdx.x * blockDim.x + threadIdx.x) * 8;
  long stride = (long)gridDim.x * blockDim.x * 8;
  for (long i = i0; i < n; i += stride) {
    int4 a = *(const int4*)(w + i);
    int4 b = *(const int4*)(w + i + 4);
    bf16x8 o;
    o[0] = (short)i2bf(a.x); o[1] = (short)i2bf(a.y);
    o[2] = (short)i2bf(a.z); o[3] = (short)i2bf(a.w);
    o[4] = (short)i2bf(b.x); o[5] = (short)i2bf(b.y);
    o[6] = (short)i2bf(b.z); o[7] = (short)i2bf(b.w);
    *(bf16x8*)(wb + i) = o;
  }
}

// ---------------- 256x256 GEMM: A in LDS, B direct-from-L2 ----------------
// 512 threads = 8 waves (2 wr x 4 wc). Wave tile 128x64 = 8x4 frags 16x16x32.
// LDS 64 KiB = A only, double-buffered: AOFF(b,mh) bytes = b*32768 + mh*16384
//   (128 rows x 128 B). Swizzle: stored_byte = logical ^ ((row&7)<<4);
//   staged via inverse-swizzled GLOBAL source + linear dest (rule 21).
//   All A-read addressing = ONE base reg (+^64 for kk) + 16-bit imm
//   (buf*32768 + mh*16384 + mi*2048) — imm bits >=11 don't touch swizzle.
// B frags: per-lane global_load_dwordx4 at voff[nh][ni] + imm {0,64} (kk) +
//   T*128 (reg increment). Lane (fr,fq): row wc*64+nh*32+ni*16+fr, bytes
//   fq*16. Per tile each touched 128-B line is fully consumed (kk0+kk1).
// Phase schedule per tile T (buf CB = T&1):
//   q0: glb bF1(T); LGKM(0) [aFx]; VMW(4) [bF0(T)+T+1 A-stages]; MFMA(aFx,bF0)
//   q1: rd aFy (CB,mh1); stage A-mh0(T+2)->CB; VMW(2) [bF1]; MFMA(aFx,bF1)
//   q2: LGKM(0) [aFy]; MFMA(aFy,bF1)
//   q3: rd aFx(T+1) (NB,mh0); stage A-mh1(T+2)->CB; MFMA(aFy,bF0);
//       glb bF0(T+1) imm+128; vb+=128
// WAR safety: each stage targets the region whose reads drained at the
// preceding phase's LGKM(0) + barrier (R5-proven pattern).

#define DSR(dst, base, OFF)                                     \
  asm volatile("ds_read_b128 %0, %1 offset:" OFF                \
               : "=v"(dst) : "v"(base))
#define GLB(dst, voff, ptr, OFF)                                \
  asm volatile("global_load_dwordx4 %0, %1, %2 offset:" OFF     \
               : "=v"(dst) : "v"(voff), "s"(ptr))
#define LGKM(N)                                                 \
  asm volatile("s_waitcnt lgkmcnt(" #N ")" ::: "memory");       \
  __builtin_amdgcn_sched_barrier(0)
#define VMWS(N)                                                 \
  asm volatile("s_waitcnt vmcnt(" #N ")" ::: "memory");         \
  __builtin_amdgcn_sched_barrier(0)

// 8 ds_read_b128: 4 mi x 2 kk. Base rA0 / rA1(=rA0^64); imms X + mi*2048.
#define RD_A8(AF, B0, B1, O0, O1, O2, O3)                       \
  do {                                                          \
    DSR(AF[0][0], B0, O0); DSR(AF[0][1], B1, O0);               \
    DSR(AF[1][0], B0, O1); DSR(AF[1][1], B1, O1);               \
    DSR(AF[2][0], B0, O2); DSR(AF[2][1], B1, O2);               \
    DSR(AF[3][0], B0, O3); DSR(AF[3][1], B1, O3);               \
  } while (0)

#define MFMA16(AF, BF, MH, NH)                                                 \
  do {                                                                         \
    __builtin_amdgcn_s_setprio(1);                                             \
    _Pragma("unroll") for (int kk = 0; kk < 2; ++kk)                           \
    _Pragma("unroll") for (int mi = 0; mi < 4; ++mi)                           \
    _Pragma("unroll") for (int ni = 0; ni < 2; ++ni)                           \
      acc[(MH)*4 + mi][(NH)*2 + ni] = __builtin_amdgcn_mfma_f32_16x16x32_bf16( \
          AF[mi][kk], BF[ni][kk], acc[(MH)*4 + mi][(NH)*2 + ni], 0, 0, 0);     \
    __builtin_amdgcn_s_setprio(0);                                             \
    __builtin_amdgcn_sched_barrier(0);                                         \
  } while (0)

__device__ __forceinline__ void stage_A_half(const unsigned short* __restrict__ A,
                                             int grow0, int ktE, int mh,
                                             unsigned short* lds_region, int t) {
  const int colb = (t & 7) * 16;
  const int swz = ((t >> 3) & 7) << 4;
  const int scol = (colb ^ swz) >> 1;
#pragma unroll
  for (int rr = 0; rr < 2; ++rr) {
    int rho = rr * 64 + (t >> 3);
    int r = ((rho >> 6) << 7) + mh * 64 + (rho & 63);
    async16(A + (size_t)(grow0 + r) * K_DIM + ktE + scol,
            lds_region + rr * 4096 + t * 8);
  }
}

// Main-loop tile: CB = buf of T (0/1). O1* = aFy imms (CB,mh1); O3* = aFx
// imms for T+1 (buf CB^1, mh0).
#define TILE(TT, CB, O1A, O1B, O1C, O1D, O3A, O3B, O3C, O3D)                   \
  do {                                                                         \
    const int T_ = (TT);                                                       \
    /* q0 */                                                                   \
    GLB(bF1[0][0], vb10, Bblk, "0");  GLB(bF1[0][1], vb10, Bblk, "64");        \
    GLB(bF1[1][0], vb11, Bblk, "0");  GLB(bF1[1][1], vb11, Bblk, "64");        \
    LGKM(0);                                                                   \
    VMWS(4);                                                                   \
    MFMA16(aFx, bF0, 0, 0);                                                    \
    __builtin_amdgcn_s_barrier();                                              \
    /* q1 */                                                                   \
    RD_A8(aFy, rA0, rA1, O1A, O1B, O1C, O1D);                                  \
    stage_A_half(A, brow, (T_ + 2) * BK, 0, lds + (CB)*16384, t);              \
    VMWS(2);                                                                   \
    MFMA16(aFx, bF1, 0, 1);                                                    \
    __builtin_amdgcn_s_barrier();                                              \
    /* q2 */                                                                   \
    LGKM(0);                                                                   \
    MFMA16(aFy, bF1, 1, 1);                                                    \
    __builtin_amdgcn_s_barrier();                                              \
    /* q3 */                                                                   \
    RD_A8(aFx, rA0, rA1, O3A, O3B, O3C, O3D);                                  \
    stage_A_half(A, brow, (T_ + 2) * BK, 1, lds + (CB)*16384 + 8192, t);       \
    MFMA16(aFy, bF0, 1, 0);                                                    \
    GLB(bF0[0][0], vb00, Bblk, "128"); GLB(bF0[0][1], vb00, Bblk, "192");      \
    GLB(bF0[1][0], vb01, Bblk, "128"); GLB(bF0[1][1], vb01, Bblk, "192");      \
    vb00 += 128u; vb01 += 128u; vb10 += 128u; vb11 += 128u;                    \
    __builtin_amdgcn_s_barrier();                                              \
  } while (0)

__global__ void __launch_bounds__(512, 2)
gemm_bt_kernel(const unsigned short* __restrict__ A,  // bf16 [M][K]
               const unsigned short* __restrict__ B,  // bf16 [N][K]
               const float* __restrict__ scale, const float* __restrict__ bias,
               float* __restrict__ C) {
  __shared__ unsigned short lds[32768];  // 64 KiB (A only, dbuf)

  const int t = threadIdx.x;
  const int bid = blockIdx.x;
  const int swz = (bid & 7) * 64 + (bid >> 3);  // 512 wgs, 64/XCD (bijective)
  const int bm = swz >> 4;  // 32 M-tiles
  const int bn = swz & 15;  // 16 N-tiles
  const int brow = bm * 256, bcol = bn * 256;

  const int wid = t >> 6, lane = t & 63;
  const int wr = wid >> 2, wc = wid & 3;
  const int fr = lane & 15, fq = lane >> 4;

  // A LDS read bases (swizzle folded; kk via ^64; buf/mh/mi via 16-bit imm)
  const unsigned ldsb = (unsigned)(unsigned long long)&lds[0];
  const unsigned rA0 = ldsb + (unsigned)((wr * 64 + fr) * 128) +
                       (((unsigned)(fq * 16)) ^ ((unsigned)((fr & 7) << 4)));
  const unsigned rA1 = rA0 ^ 64u;

  // B global voffsets per (nh, ni); kk via imm {0,64}; T via reg increment
  const unsigned short* Bblk = B + (size_t)bcol * K_DIM;
  unsigned vb00 = (unsigned)((wc * 64 + 0 + fr) * 8192 + fq * 16);
  unsigned vb01 = (unsigned)((wc * 64 + 16 + fr) * 8192 + fq * 16);
  unsigned vb10 = (unsigned)((wc * 64 + 32 + fr) * 8192 + fq * 16);
  unsigned vb11 = (unsigned)((wc * 64 + 48 + fr) * 8192 + fq * 16);

  f32x4 acc[8][4] = {};
  bf16x8 aFx[4][2], aFy[4][2], bF0[2][2], bF1[2][2];

  // ---- prologue: stage A tiles 0,1; load bF0(0); read aFx(0) ----
  stage_A_half(A, brow, 0, 0, lds, t);
  stage_A_half(A, brow, 0, 1, lds + 8192, t);
  stage_A_half(A, brow, BK, 0, lds + 16384, t);
  stage_A_half(A, brow, BK, 1, lds + 24576, t);
  GLB(bF0[0][0], vb00, Bblk, "0"); GLB(bF0[0][1], vb00, Bblk, "64");
  GLB(bF0[1][0], vb01, Bblk, "0"); GLB(bF0[1][1], vb01, Bblk, "64");
  VMWS(8);  // tile0 A halves landed
  __builtin_amdgcn_s_barrier();
  RD_A8(aFx, rA0, rA1, "0", "2048", "4096", "6144");  // buf0 mh0

  // ---- main loop: tiles 0..NT-3 (branch-free; stages/prefetch always valid)
  for (int T = 0; T < NT - 2; T += 2) {
    TILE(T, 0, "16384", "18432", "20480", "22528",   // aFy: buf0 mh1
               "32768", "34816", "36864", "38912");  // aFx(T+1): buf1 mh0
    TILE(T + 1, 1, "49152", "51200", "53248", "55296",  // aFy: buf1 mh1
                   "0", "2048", "4096", "6144");        // aFx(T+2): buf0 mh0
  }

  // ---- tail tile NT-2 (buf0): no stages, conservative waits ----
  GLB(bF1[0][0], vb10, Bblk, "0");  GLB(bF1[0][1], vb10, Bblk, "64");
  GLB(bF1[1][0], vb11, Bblk, "0");  GLB(bF1[1][1], vb11, Bblk, "64");
  LGKM(0); VMWS(0);
  MFMA16(aFx, bF0, 0, 0);
  __builtin_amdgcn_s_barrier();
  RD_A8(aFy, rA0, rA1, "16384", "18432", "20480", "22528");
  VMWS(0);
  MFMA16(aFx, bF1, 0, 1);
  __builtin_amdgcn_s_barrier();
  LGKM(0);
  MFMA16(aFy, bF1, 1, 1);
  __builtin_amdgcn_s_barrier();
  RD_A8(aFx, rA0, rA1, "32768", "34816", "36864", "38912");
  MFMA16(aFy, bF0, 1, 0);
  GLB(bF0[0][0], vb00, Bblk, "128"); GLB(bF0[0][1], vb00, Bblk, "192");
  GLB(bF0[1][0], vb01, Bblk, "128"); GLB(bF0[1][1], vb01, Bblk, "192");
  __builtin_amdgcn_s_barrier();

  // ---- tail tile NT-1 (buf1) ----
  GLB(bF1[0][0], vb10, Bblk, "128"); GLB(bF1[0][1], vb10, Bblk, "192");
  GLB(bF1[1][0], vb11, Bblk, "128"); GLB(bF1[1][1], vb11, Bblk, "192");
  LGKM(0); VMWS(0);
  MFMA16(aFx, bF0, 0, 0);
  __builtin_amdgcn_s_barrier();
  RD_A8(aFy, rA0, rA1, "49152", "51200", "53248", "55296");
  VMWS(0);
  MFMA16(aFx, bF1, 0, 1);
  __builtin_amdgcn_s_barrier();
  LGKM(0);
  MFMA16(aFy, bF1, 1, 1);
  __builtin_amdgcn_s_barrier();
  LGKM(0);
  MFMA16(aFy, bF0, 1, 0);

  // ---- epilogue: scale/bias, C/D layout col=lane&15, row=(lane>>4)*4+j ----
#pragma unroll
  for (int n = 0; n < 4; ++n) {
    const int gc = bcol + wc * 64 + n * 16 + fr;
    const float s = scale[gc];
    const float bo = bias[gc];
#pragma unroll
    for (int m = 0; m < 8; ++m) {
      const int gr = brow + wr * 128 + m * 16 + fq * 4;
#pragma unroll
      for (int j = 0; j < 4; ++j)
        C[(size_t)(gr + j) * N_DIM + gc] = acc[m][n][j] * s + bo;
    }
  }
}

// ---------------- naive fallback (only if ws too small) ----------------

__global__ void naive_kernel(const float* __restrict__ x, const int* __restrict__ w,
                             const float* __restrict__ sc, const float* __restrict__ bi,
                             float* __restrict__ out) {
  size_t idx = (size_t)blockIdx.x * blockDim.x + threadIdx.x;
  int m = (int)(idx >> 12);
  int n = (int)(idx & 4095);
  const float* xr = x + (size_t)m * K_DIM;
  const int* wr = w + (size_t)n * K_DIM;
  float acc = 0.f;
  for (int k = 0; k < K_DIM; ++k) acc = fmaf(xr[k], (float)wr[k], acc);
  out[idx] = acc * sc[n] + bi[n];
}

extern "C" void kernel_launch(void* const* d_in, const int* in_sizes, int n_in,
                              void* d_out, int out_size, void* d_ws, size_t ws_size,
                              hipStream_t stream) {
  const float* x = (const float*)d_in[0];
  const int* w = (const int*)d_in[1];
  const float* scale = (const float*)d_in[2];
  const float* bias = (const float*)d_in[3];
  float* out = (float*)d_out;

  const long nx = (long)M_DIM * K_DIM;
  const long nw = (long)N_DIM * K_DIM;
  const size_t need = (size_t)nx * 2 + (size_t)nw * 2;  // 96 MiB

  if (ws_size >= need) {
    unsigned short* xb = (unsigned short*)d_ws;
    unsigned short* wb = xb + nx;
    cvt_x_kernel<<<2048, 256, 0, stream>>>(x, xb, nx);
    cvt_w_kernel<<<2048, 256, 0, stream>>>(w, wb, nw);
    gemm_bt_kernel<<<512, 512, 0, stream>>>(xb, wb, scale, bias, out);
  } else {
    naive_kernel<<<((long)M_DIM * N_DIM) / 256, 256, 0, stream>>>(x, w, scale, bias, out);
  }
}